// Round 7
// baseline (209.870 us; speedup 1.0000x reference)
//
#include <hip/hip_runtime.h>

#define INV_N2 (1.0f/262144.0f)
#define HALF_INV (0.5f*INV_N2)
#define TP 17                         // fwd_rows LDS row-tile stride (16 rows + 1 pad)
#define YT_B ((size_t)(264 * 512))    // Yt batch stride in float2
#define Y2N 520                       // Yt2 n-dimension (512 used + dump slot 513 + pad)

typedef unsigned u32x2 __attribute__((ext_vector_type(2)));
typedef float v2f __attribute__((ext_vector_type(2)));

__device__ __forceinline__ v2f v2(float a, float b) { v2f r; r.x = a; r.y = b; return r; }
__device__ __forceinline__ int brev9(int v) { return (int)(__brev((unsigned)v) >> 23); }
__device__ __forceinline__ float hsin(float rev) { return __builtin_amdgcn_sinf(rev); }
__device__ __forceinline__ float hcos(float rev) { return __builtin_amdgcn_cosf(rev); }

// ---------------- cross-lane exchange ----------------
template<int CTRL>
__device__ __forceinline__ float xdpp(float x) {
  int v = __float_as_int(x);
  return __int_as_float(__builtin_amdgcn_update_dpp(v, v, CTRL, 0xF, 0xF, true));
}
__device__ __forceinline__ float xs1(float x) { return xdpp<0xB1>(x); }   // quad_perm [1,0,3,2]
__device__ __forceinline__ float xs2(float x) { return xdpp<0x4E>(x); }   // quad_perm [2,3,0,1]
__device__ __forceinline__ float xs8(float x) { return xdpp<0x128>(x); }  // row_ror:8
__device__ __forceinline__ float xs4(float x) {
  return __int_as_float(__builtin_amdgcn_ds_swizzle(__float_as_int(x), 0x101F));
}
// Swap exchanges: return BOTH halves (lo = value at lane&~S, hi = value at lane|S).
__device__ __forceinline__ void swp16(float x, float &lo, float &hi) {
#if __has_builtin(__builtin_amdgcn_permlane16_swap)
  u32x2 r = __builtin_amdgcn_permlane16_swap(__float_as_uint(x), __float_as_uint(x), false, false);
  lo = __uint_as_float(r[0]); hi = __uint_as_float(r[1]);
#else
  float p = __int_as_float(__builtin_amdgcn_ds_swizzle(__float_as_int(x), 0x401F));
  bool up = (threadIdx.x & 16) != 0;
  lo = up ? p : x; hi = up ? x : p;
#endif
}
__device__ __forceinline__ void swp32(float x, float &lo, float &hi) {
#if __has_builtin(__builtin_amdgcn_permlane32_swap)
  u32x2 r = __builtin_amdgcn_permlane32_swap(__float_as_uint(x), __float_as_uint(x), false, false);
  lo = __uint_as_float(r[0]); hi = __uint_as_float(r[1]);
#else
  float p = __shfl_xor(x, 32, 64);
  bool up = (threadIdx.x & 32) != 0;
  lo = up ? p : x; hi = up ? x : p;
#endif
}

// ---------------- per-lane stage twiddles ----------------
struct Tw { float c[8], s[8]; };
__device__ __forceinline__ Tw make_tw(int lane) {
  Tw t;
  float a0 = (float)lane        * (1.0f/512.0f);
  float a1 = (float)lane        * (1.0f/256.0f);
  float a2 = (float)lane        * (1.0f/128.0f);
  float a3 = (float)(lane & 31) * (1.0f/64.0f);
  float a4 = (float)(lane & 15) * (1.0f/32.0f);
  float a5 = (float)(lane & 7)  * (1.0f/16.0f);
  float a6 = (float)(lane & 3)  * (1.0f/8.0f);
  float a7 = (float)(lane & 1)  * (1.0f/4.0f);
  t.c[0]=hcos(a0); t.s[0]=hsin(a0); t.c[1]=hcos(a1); t.s[1]=hsin(a1);
  t.c[2]=hcos(a2); t.s[2]=hsin(a2); t.c[3]=hcos(a3); t.s[3]=hsin(a3);
  t.c[4]=hcos(a4); t.s[4]=hsin(a4); t.c[5]=hcos(a5); t.s[5]=hsin(a5);
  t.c[6]=hcos(a6); t.s[6]=hsin(a6); t.c[7]=hcos(a7); t.s[7]=hsin(a7);
  return t;
}

// ---------------- packed cross-lane stage macros ----------------
#define FWD_PK_XS(S, XCHG, CC, SS) { \
  const bool up = (lane & (S)) != 0; \
  const float sg = up ? -1.0f : 1.0f; \
  const float wr = up ? (CC) : 1.0f; \
  const float wi = up ? -(SS) : 0.0f; \
  const v2f sgv = v2(sg,sg), wrv = v2(wr,wr), wiv = v2(wi,wi); \
  _Pragma("unroll") for (int j = 0; j < 4; ++j) { \
    v2f Rr = v2(XCHG(Xr[j].x), XCHG(Xr[j].y)); \
    v2f Ri = v2(XCHG(Xi[j].x), XCHG(Xi[j].y)); \
    v2f vr = sgv*Xr[j] + Rr; v2f vi = sgv*Xi[j] + Ri; \
    Xr[j] = vr*wrv - vi*wiv; Xi[j] = vr*wiv + vi*wrv; } }

#define FWD_PK_SW(S, SWP, CC, SS) { \
  const bool up = (lane & (S)) != 0; \
  const float sg = up ? -1.0f : 1.0f; \
  const float wr = up ? (CC) : 1.0f; \
  const float wi = up ? -(SS) : 0.0f; \
  const v2f sgv = v2(sg,sg), wrv = v2(wr,wr), wiv = v2(wi,wi); \
  _Pragma("unroll") for (int j = 0; j < 4; ++j) { \
    float l0,h0,l1,h1; \
    SWP(Xr[j].x,l0,h0); SWP(Xr[j].y,l1,h1); \
    v2f Lr = v2(l0,l1), Hr = v2(h0,h1); \
    SWP(Xi[j].x,l0,h0); SWP(Xi[j].y,l1,h1); \
    v2f Li = v2(l0,l1), Hi = v2(h0,h1); \
    v2f vr = sgv*Hr + Lr; v2f vi = sgv*Hi + Li; \
    Xr[j] = vr*wrv - vi*wiv; Xi[j] = vr*wiv + vi*wrv; } }

#define INV_PK_XS(S, XCHG, CC, SS) { \
  const bool up = (lane & (S)) != 0; \
  const float wr = up ? (CC) : 1.0f; \
  const float wi = up ? (SS) : 0.0f; \
  const float sg = up ? -1.0f : 1.0f; \
  const v2f sgv = v2(sg,sg), wrv = v2(wr,wr), wiv = v2(wi,wi); \
  _Pragma("unroll") for (int j = 0; j < 4; ++j) { \
    v2f Zr = Xr[j]*wrv - Xi[j]*wiv; \
    v2f Zi = Xr[j]*wiv + Xi[j]*wrv; \
    v2f Rr = v2(XCHG(Zr.x), XCHG(Zr.y)); \
    v2f Ri = v2(XCHG(Zi.x), XCHG(Zi.y)); \
    Xr[j] = sgv*Zr + Rr; Xi[j] = sgv*Zi + Ri; } }

#define INV_PK_SW(S, SWP, CC, SS) { \
  const bool up = (lane & (S)) != 0; \
  const float wr = up ? (CC) : 1.0f; \
  const float wi = up ? (SS) : 0.0f; \
  const float sg = up ? -1.0f : 1.0f; \
  const v2f sgv = v2(sg,sg), wrv = v2(wr,wr), wiv = v2(wi,wi); \
  _Pragma("unroll") for (int j = 0; j < 4; ++j) { \
    v2f Zr = Xr[j]*wrv - Xi[j]*wiv; \
    v2f Zi = Xr[j]*wiv + Xi[j]*wrv; \
    float l0,h0,l1,h1; \
    SWP(Zr.x,l0,h0); SWP(Zr.y,l1,h1); \
    v2f Lr = v2(l0,l1), Hr = v2(h0,h1); \
    SWP(Zi.x,l0,h0); SWP(Zi.y,l1,h1); \
    v2f Li = v2(l0,l1), Hi = v2(h0,h1); \
    Xr[j] = sgv*Hr + Lr; Xi[j] = sgv*Hi + Li; } }

// Forward DIF: natural in -> bit-reversed out.
__device__ __forceinline__ void wave_fft512_fwd(v2f Xr[4], v2f Xi[4], int lane,
                                                const Tw& t) {
  { // s=256: packed per-k twiddles; Tr1=Ti0, Ti1=-Tr0
    const float c8 = 0.70710678118654752f;
    float wr = t.c[0], wi = -t.s[0];
    float w1r = c8*(wr + wi), w1i = c8*(wi - wr);
    v2f Tr0 = v2(wr, w1r), Ti0 = v2(wi, w1i);
    { v2f Sr = Xr[0]+Xr[2], Si = Xi[0]+Xi[2];
      v2f Dr = Xr[0]-Xr[2], Di = Xi[0]-Xi[2];
      Xr[0] = Sr; Xi[0] = Si;
      Xr[2] = Dr*Tr0 - Di*Ti0; Xi[2] = Dr*Ti0 + Di*Tr0; }
    { v2f Sr = Xr[1]+Xr[3], Si = Xi[1]+Xi[3];
      v2f Dr = Xr[1]-Xr[3], Di = Xi[1]-Xi[3];
      Xr[1] = Sr; Xi[1] = Si;
      Xr[3] = Dr*Ti0 + Di*Tr0; Xi[3] = Di*Ti0 - Dr*Tr0; }
  }
  { // s=128
    v2f Tr = v2(t.c[1], -t.s[1]), Ti = v2(-t.s[1], -t.c[1]);
    #pragma unroll
    for (int j = 0; j < 4; j += 2) {
      v2f Sr = Xr[j]+Xr[j+1], Si = Xi[j]+Xi[j+1];
      v2f Dr = Xr[j]-Xr[j+1], Di = Xi[j]-Xi[j+1];
      Xr[j] = Sr; Xi[j] = Si;
      Xr[j+1] = Dr*Tr - Di*Ti; Xi[j+1] = Dr*Ti + Di*Tr;
    }
  }
  { // s=64: intra-pair, scalar
    float wr = t.c[2], wi = -t.s[2];
    #pragma unroll
    for (int j = 0; j < 4; ++j) {
      float sr = Xr[j].x + Xr[j].y, si = Xi[j].x + Xi[j].y;
      float dr = Xr[j].x - Xr[j].y, di = Xi[j].x - Xi[j].y;
      Xr[j] = v2(sr, dr*wr - di*wi);
      Xi[j] = v2(si, dr*wi + di*wr);
    }
  }
  FWD_PK_SW(32, swp32, t.c[3], t.s[3])
  FWD_PK_SW(16, swp16, t.c[4], t.s[4])
  FWD_PK_XS(8,  xs8,  t.c[5], t.s[5])
  FWD_PK_XS(4,  xs4,  t.c[6], t.s[6])
  FWD_PK_XS(2,  xs2,  t.c[7], t.s[7])
  { // s=1
    const float sg = (lane & 1) ? -1.0f : 1.0f;
    const v2f sgv = v2(sg, sg);
    #pragma unroll
    for (int j = 0; j < 4; ++j) {
      v2f Rr = v2(xs1(Xr[j].x), xs1(Xr[j].y));
      v2f Ri = v2(xs1(Xi[j].x), xs1(Xi[j].y));
      Xr[j] = sgv*Xr[j] + Rr; Xi[j] = sgv*Xi[j] + Ri;
    }
  }
}

// Inverse DIT: bit-reversed in -> natural out (unnormalized).
__device__ __forceinline__ void wave_fft512_inv(v2f Xr[4], v2f Xi[4], int lane,
                                                const Tw& t) {
  { // s=1
    const float sg = (lane & 1) ? -1.0f : 1.0f;
    const v2f sgv = v2(sg, sg);
    #pragma unroll
    for (int j = 0; j < 4; ++j) {
      v2f Rr = v2(xs1(Xr[j].x), xs1(Xr[j].y));
      v2f Ri = v2(xs1(Xi[j].x), xs1(Xi[j].y));
      Xr[j] = sgv*Xr[j] + Rr; Xi[j] = sgv*Xi[j] + Ri;
    }
  }
  INV_PK_XS(2,  xs2,  t.c[7], t.s[7])
  INV_PK_XS(4,  xs4,  t.c[6], t.s[6])
  INV_PK_XS(8,  xs8,  t.c[5], t.s[5])
  INV_PK_SW(16, swp16, t.c[4], t.s[4])
  INV_PK_SW(32, swp32, t.c[3], t.s[3])
  { // s=64: intra-pair, scalar
    float wr = t.c[2], wi = t.s[2];
    #pragma unroll
    for (int j = 0; j < 4; ++j) {
      float tr = Xr[j].y*wr - Xi[j].y*wi, ti = Xr[j].y*wi + Xi[j].y*wr;
      Xr[j] = v2(Xr[j].x + tr, Xr[j].x - tr);
      Xi[j] = v2(Xi[j].x + ti, Xi[j].x - ti);
    }
  }
  { // s=128
    v2f Tr = v2(t.c[1], -t.s[1]), Ti = v2(t.s[1], t.c[1]);
    #pragma unroll
    for (int j = 0; j < 4; j += 2) {
      v2f tr = Xr[j+1]*Tr - Xi[j+1]*Ti;
      v2f ti = Xr[j+1]*Ti + Xi[j+1]*Tr;
      Xr[j+1] = Xr[j] - tr; Xi[j+1] = Xi[j] - ti;
      Xr[j]   = Xr[j] + tr; Xi[j]   = Xi[j] + ti;
    }
  }
  { // s=256
    const float c8 = 0.70710678118654752f;
    float wr = t.c[0], wi = t.s[0];
    float w1r = c8*(wr - wi), w1i = c8*(wr + wi);
    v2f Tr0 = v2(wr, w1r), Ti0 = v2(wi, w1i);
    { v2f tr = Xr[2]*Tr0 - Xi[2]*Ti0;
      v2f ti = Xr[2]*Ti0 + Xi[2]*Tr0;
      Xr[2] = Xr[0] - tr; Xi[2] = Xi[0] - ti;
      Xr[0] = Xr[0] + tr; Xi[0] = Xi[0] + ti; }
    { v2f tr = -(Xr[3]*Ti0) - Xi[3]*Tr0;
      v2f ti = Xr[3]*Tr0 - Xi[3]*Ti0;
      Xr[3] = Xr[1] - tr; Xi[3] = Xi[1] - ti;
      Xr[1] = Xr[1] + tr; Xi[1] = Xi[1] + ti; }
  }
}

// ---------------- kernels ----------------
__global__ void k_scatter(const int* __restrict__ idxx, const int* __restrict__ idxy,
                          const int* __restrict__ cid, int* __restrict__ W) {
  int p = blockIdx.x * 256 + threadIdx.x;
  int u = (idxx[p] + 256) & 511;
  int v = (idxy[p] + 256) & 511;
  atomicMax(&W[u * 512 + v], (p << 6) | cid[p]);
}

__global__ void k_pack(const int* __restrict__ W, int* __restrict__ pk) {
  int idx = blockIdx.x * 256 + threadIdx.x;
  if (idx >= 264 * 512) return;
  int j = idx >> 9, n = idx & 511;
  int out = (127 << 7) | 127;
  if (j < 257) {
    int v = (j == 256) ? 256 : brev9(2 * j);
    int u = brev9(n);
    int c1 = W[u * 512 + v];
    int c2 = W[((512 - u) & 511) * 512 + ((512 - v) & 511)];
    int a = (c1 < 0) ? 127 : (c1 & 63);
    int b = (c2 < 0) ? 127 : (c2 & 63);
    out = (b << 7) | a;
  }
  pk[j * 512 + n] = out;
}

// Two real rows per complex FFT; output TRANSPOSED: Yt[b][j][r].
__global__ __launch_bounds__(512) void k_fwd_rows(const float* __restrict__ x,
                                                  float2* __restrict__ Yt) {
  __shared__ float sm[2 * 264 * TP];
  float* tR = sm;
  float* tI = sm + 264 * TP;
  int tid = threadIdx.x, w = tid >> 6, lane = tid & 63;
  int R0 = blockIdx.x * 16;
  int bb = R0 >> 9, r0 = R0 & 511;
  const float* rowA = x + (size_t)(R0 + 2 * w) * 512;
  const float* rowB = rowA + 512;
  Tw t = make_tw(lane);
  v2f Xr[4], Xi[4];
  #pragma unroll
  for (int j = 0; j < 4; ++j) {
    Xr[j] = v2(rowA[(2*j)*64 + lane], rowA[(2*j+1)*64 + lane]);
    Xi[j] = v2(rowB[(2*j)*64 + lane], rowB[(2*j+1)*64 + lane]);
  }
  wave_fft512_fwd(Xr, Xi, lane, t);
  float* zr = sm + w * 1024;                     // wave-private scratch (in-order DS)
  float* zi = zr + 512;
  #pragma unroll
  for (int j = 0; j < 4; ++j) {
    zr[(2*j)*64 + lane] = Xr[j].x; zr[(2*j+1)*64 + lane] = Xr[j].y;
    zi[(2*j)*64 + lane] = Xi[j].x; zi[(2*j+1)*64 + lane] = Xi[j].y;
  }
  float ar[4], ai[4], br[4], bi[4];
  #pragma unroll
  for (int k = 0; k < 4; ++k) {                  // split A/B half-spectra
    int j = k * 64 + lane;
    int n2 = 2 * j;
    int kf = brev9(n2);
    int m = brev9((512 - kf) & 511);
    float er = zr[n2], ei = zi[n2];
    float mr = zr[m],  mi = zi[m];
    ar[k] = 0.5f * (er + mr); ai[k] = 0.5f * (ei - mi);
    br[k] = 0.5f * (ei + mi); bi[k] = 0.5f * (mr - er);
  }
  float a256 = zr[1], b256 = zi[1];
  __syncthreads();
  #pragma unroll
  for (int k = 0; k < 4; ++k) {
    int j = k * 64 + lane;
    tR[j*TP + 2*w]     = ar[k]; tI[j*TP + 2*w]     = ai[k];
    tR[j*TP + 2*w + 1] = br[k]; tI[j*TP + 2*w + 1] = bi[k];
  }
  if (lane == 0) {
    tR[256*TP + 2*w]     = a256; tI[256*TP + 2*w]     = 0.0f;
    tR[256*TP + 2*w + 1] = b256; tI[256*TP + 2*w + 1] = 0.0f;
  }
  __syncthreads();
  #pragma unroll
  for (int rep = 0; rep < 9; ++rep) {
    int e = rep * 512 + tid;
    int j = e >> 4, rr = e & 15;
    if (j < 257)
      Yt[((size_t)bb * 264 + j) * 512 + r0 + rr] =
        make_float2(tR[j*TP + rr], tI[j*TP + rr]);
  }
}

// Column FFT + symmetrized mask + inverse column FFT + Hermitian C-merge.
// Writes C directly into inv-ready layout: Yt2[(rp>>3)][n][rp&7].
__global__ __launch_bounds__(512) void k_cols(const float2* __restrict__ Yt,
                                              float2* __restrict__ Yt2,
                                              const int* __restrict__ pk,
                                              const float* __restrict__ pimp) {
  __shared__ float pilx[128];
  int tid = threadIdx.x;
  int b = blockIdx.x / 33, g = blockIdx.x % 33;
  if (tid < 128) pilx[tid] = (tid < 64) ? pimp[b * 64 + tid] * HALF_INV : HALF_INV;
  int w = tid >> 6, lane = tid & 63;
  int j = g * 8 + w;
  const float2* col = Yt + ((size_t)b * 264 + j) * 512;
  const int* cm = pk + j * 512;
  int pcm[8];
  v2f Xr[4], Xi[4];
  #pragma unroll
  for (int q = 0; q < 4; ++q) {                  // coalesced loads + pk prefetch
    float2 v0 = col[(2*q)*64 + lane];
    float2 v1 = col[(2*q+1)*64 + lane];
    Xr[q] = v2(v0.x, v1.x); Xi[q] = v2(v0.y, v1.y);
    pcm[2*q]   = cm[(2*q)*64 + lane];
    pcm[2*q+1] = cm[(2*q+1)*64 + lane];
  }
  Tw t = make_tw(lane);
  wave_fft512_fwd(Xr, Xi, lane, t);
  __syncthreads();                               // pilx ready (hidden behind FFT)
  #pragma unroll
  for (int q = 0; q < 4; ++q) {                  // packed symmetrized mask
    int p0 = pcm[2*q], p1 = pcm[2*q+1];
    v2f mv = v2(pilx[p0 & 127] + pilx[(p0 >> 7) & 127],
                pilx[p1 & 127] + pilx[(p1 >> 7) & 127]);
    Xr[q] *= mv; Xi[q] *= mv;
  }
  wave_fft512_inv(Xr, Xi, lane, t);
  // Hermitian C-merge: even lanes (A') pair with odd lanes (B') of same row-pair.
  // even n_e gets (ar-bi, ai+br); odd n_o gets (ar+bi, br-ai) == component swap.
  if (j <= 256) {
    int n_e = (j == 256) ? 1 : 2 * j;
    int n_o = (j >= 1 && j <= 255) ? brev9(512 - brev9(2 * j)) : 513;  // 513 = dump
    bool odd = (lane & 1) != 0;
    int nsel = odd ? n_o : n_e;
    int rpb = b * 256 + (lane >> 1);
    #pragma unroll
    for (int q = 0; q < 4; ++q) {
      #pragma unroll
      for (int h = 0; h < 2; ++h) {
        float xr = h ? Xr[q].y : Xr[q].x;
        float xi = h ? Xi[q].y : Xi[q].x;
        float p  = xr - xs1(xi);
        float s2 = xi + xs1(xr);
        float ox = odd ? s2 : p;
        float oy = odd ? p  : s2;
        int rp = rpb + (2*q + h) * 32;
        Yt2[((size_t)(rp >> 3) * Y2N + nsel) * 8 + (rp & 7)] = make_float2(ox, oy);
      }
    }
  }
}

// Inverse row FFT from pre-merged C: contiguous load, conflict-free tile, no index math.
__global__ __launch_bounds__(512) void k_inv_rows(const float2* __restrict__ Yt2,
                                                  float* __restrict__ out) {
  __shared__ float tR[512 * 9], tI[512 * 9];     // stride 9: conflict-free reads
  int tid = threadIdx.x, w = tid >> 6, lane = tid & 63;
  int g = blockIdx.x;                            // 8 row-pairs per block
  const float4* src = (const float4*)(Yt2 + (size_t)g * Y2N * 8);
  #pragma unroll
  for (int rep = 0; rep < 4; ++rep) {            // fully contiguous 32 KB block load
    int m = rep * 512 + tid;                     // m = n*4 + c
    int n = m >> 2, c = m & 3;
    float4 v = src[m];
    tR[n*9 + 2*c]     = v.x; tI[n*9 + 2*c]     = v.y;
    tR[n*9 + 2*c + 1] = v.z; tI[n*9 + 2*c + 1] = v.w;
  }
  Tw t = make_tw(lane);
  __syncthreads();
  v2f Xr[4], Xi[4];
  #pragma unroll
  for (int q = 0; q < 4; ++q) {
    int n0 = (2*q)*64 + lane, n1 = (2*q+1)*64 + lane;
    Xr[q] = v2(tR[n0*9 + w], tR[n1*9 + w]);
    Xi[q] = v2(tI[n0*9 + w], tI[n1*9 + w]);
  }
  wave_fft512_inv(Xr, Xi, lane, t);
  float* orowA = out + (size_t)(g * 16 + 2 * w) * 512;
  float* orowB = orowA + 512;
  #pragma unroll
  for (int q = 0; q < 4; ++q) {
    orowA[(2*q)*64 + lane]   = Xr[q].x;
    orowA[(2*q+1)*64 + lane] = Xr[q].y;
    orowB[(2*q)*64 + lane]   = Xi[q].x;
    orowB[(2*q+1)*64 + lane] = Xi[q].y;
  }
}

extern "C" void kernel_launch(void* const* d_in, const int* in_sizes, int n_in,
                              void* d_out, int out_size, void* d_ws, size_t ws_size,
                              hipStream_t stream) {
  const float* x    = (const float*)d_in[0];
  const float* pimp = (const float*)d_in[1];
  const int* idxx   = (const int*)d_in[2];
  const int* idxy   = (const int*)d_in[3];
  const int* cid    = (const int*)d_in[4];

  float2* Yt = (float2*)d_ws;                                    // 69.2 MB
  int* W  = (int*)((char*)d_ws + (size_t)64 * YT_B * sizeof(float2)); // 1 MB
  int* pk = W + 512 * 512;                                       // 0.54 MB
  float2* Yt2 = (float2*)((char*)d_ws + (size_t)72 * 1024 * 1024);    // 2048*520*8*8B = 68.2 MB

  hipMemsetAsync(W, 0xFF, 512 * 512 * sizeof(int), stream);
  k_scatter  <<<1024, 256, 0, stream>>>(idxx, idxy, cid, W);
  k_pack     <<<(264 * 512 + 255) / 256, 256, 0, stream>>>(W, pk);
  k_fwd_rows <<<2048, 512, 0, stream>>>(x, Yt);
  k_cols     <<<64 * 33, 512, 0, stream>>>(Yt, Yt2, pk, pimp);
  k_inv_rows <<<2048, 512, 0, stream>>>(Yt2, (float*)d_out);
}

// Round 8
// 195.966 us; speedup vs baseline: 1.0709x; 1.0709x over previous
//
#include <hip/hip_runtime.h>

#define INV_N2 (1.0f/262144.0f)
#define HALF_INV (0.5f*INV_N2)
#define TP 17                         // LDS row-tile stride (16 rows + 1 pad)
#define YT_B ((size_t)(264 * 512))    // Yt batch stride in float2

typedef unsigned u32x2 __attribute__((ext_vector_type(2)));
typedef float v2f __attribute__((ext_vector_type(2)));

__device__ __forceinline__ v2f v2(float a, float b) { v2f r; r.x = a; r.y = b; return r; }
__device__ __forceinline__ int brev9(int v) { return (int)(__brev((unsigned)v) >> 23); }
__device__ __forceinline__ float hsin(float rev) { return __builtin_amdgcn_sinf(rev); }
__device__ __forceinline__ float hcos(float rev) { return __builtin_amdgcn_cosf(rev); }

// ---------------- cross-lane exchange ----------------
template<int CTRL>
__device__ __forceinline__ float xdpp(float x) {
  int v = __float_as_int(x);
  return __int_as_float(__builtin_amdgcn_update_dpp(v, v, CTRL, 0xF, 0xF, true));
}
__device__ __forceinline__ float xs1(float x) { return xdpp<0xB1>(x); }   // quad_perm [1,0,3,2]
__device__ __forceinline__ float xs2(float x) { return xdpp<0x4E>(x); }   // quad_perm [2,3,0,1]
__device__ __forceinline__ float xs8(float x) { return xdpp<0x128>(x); }  // row_ror:8
__device__ __forceinline__ float xs4(float x) {
  return __int_as_float(__builtin_amdgcn_ds_swizzle(__float_as_int(x), 0x101F));
}
__device__ __forceinline__ void swp16(float x, float &lo, float &hi) {
#if __has_builtin(__builtin_amdgcn_permlane16_swap)
  u32x2 r = __builtin_amdgcn_permlane16_swap(__float_as_uint(x), __float_as_uint(x), false, false);
  lo = __uint_as_float(r[0]); hi = __uint_as_float(r[1]);
#else
  float p = __int_as_float(__builtin_amdgcn_ds_swizzle(__float_as_int(x), 0x401F));
  bool up = (threadIdx.x & 16) != 0;
  lo = up ? p : x; hi = up ? x : p;
#endif
}
__device__ __forceinline__ void swp32(float x, float &lo, float &hi) {
#if __has_builtin(__builtin_amdgcn_permlane32_swap)
  u32x2 r = __builtin_amdgcn_permlane32_swap(__float_as_uint(x), __float_as_uint(x), false, false);
  lo = __uint_as_float(r[0]); hi = __uint_as_float(r[1]);
#else
  float p = __shfl_xor(x, 32, 64);
  bool up = (threadIdx.x & 32) != 0;
  lo = up ? p : x; hi = up ? x : p;
#endif
}

// ---------------- per-lane stage twiddles ----------------
struct Tw { float c[8], s[8]; };
__device__ __forceinline__ Tw make_tw(int lane) {
  Tw t;
  float a0 = (float)lane        * (1.0f/512.0f);
  float a1 = (float)lane        * (1.0f/256.0f);
  float a2 = (float)lane        * (1.0f/128.0f);
  float a3 = (float)(lane & 31) * (1.0f/64.0f);
  float a4 = (float)(lane & 15) * (1.0f/32.0f);
  float a5 = (float)(lane & 7)  * (1.0f/16.0f);
  float a6 = (float)(lane & 3)  * (1.0f/8.0f);
  float a7 = (float)(lane & 1)  * (1.0f/4.0f);
  t.c[0]=hcos(a0); t.s[0]=hsin(a0); t.c[1]=hcos(a1); t.s[1]=hsin(a1);
  t.c[2]=hcos(a2); t.s[2]=hsin(a2); t.c[3]=hcos(a3); t.s[3]=hsin(a3);
  t.c[4]=hcos(a4); t.s[4]=hsin(a4); t.c[5]=hcos(a5); t.s[5]=hsin(a5);
  t.c[6]=hcos(a6); t.s[6]=hsin(a6); t.c[7]=hcos(a7); t.s[7]=hsin(a7);
  return t;
}

// ---------------- packed cross-lane stage macros (TWO independent FFTs) ----
// State: v2f Xr[8], Xi[8]; FFT0 = regs 0..3, FFT1 = regs 4..7.
// Element n = (2j+h)*64 + lane within each FFT (j = reg index mod 4).
#define FWD_PK_XS(S, XCHG, CC, SS) { \
  const bool up = (lane & (S)) != 0; \
  const float sg = up ? -1.0f : 1.0f; \
  const float wr = up ? (CC) : 1.0f; \
  const float wi = up ? -(SS) : 0.0f; \
  const v2f sgv = v2(sg,sg), wrv = v2(wr,wr), wiv = v2(wi,wi); \
  _Pragma("unroll") for (int j = 0; j < 8; ++j) { \
    v2f Rr = v2(XCHG(Xr[j].x), XCHG(Xr[j].y)); \
    v2f Ri = v2(XCHG(Xi[j].x), XCHG(Xi[j].y)); \
    v2f vr = sgv*Xr[j] + Rr; v2f vi = sgv*Xi[j] + Ri; \
    Xr[j] = vr*wrv - vi*wiv; Xi[j] = vr*wiv + vi*wrv; } }

#define FWD_PK_SW(S, SWP, CC, SS) { \
  const bool up = (lane & (S)) != 0; \
  const float sg = up ? -1.0f : 1.0f; \
  const float wr = up ? (CC) : 1.0f; \
  const float wi = up ? -(SS) : 0.0f; \
  const v2f sgv = v2(sg,sg), wrv = v2(wr,wr), wiv = v2(wi,wi); \
  _Pragma("unroll") for (int j = 0; j < 8; ++j) { \
    float l0,h0,l1,h1; \
    SWP(Xr[j].x,l0,h0); SWP(Xr[j].y,l1,h1); \
    v2f Lr = v2(l0,l1), Hr = v2(h0,h1); \
    SWP(Xi[j].x,l0,h0); SWP(Xi[j].y,l1,h1); \
    v2f Li = v2(l0,l1), Hi = v2(h0,h1); \
    v2f vr = sgv*Hr + Lr; v2f vi = sgv*Hi + Li; \
    Xr[j] = vr*wrv - vi*wiv; Xi[j] = vr*wiv + vi*wrv; } }

#define INV_PK_XS(S, XCHG, CC, SS) { \
  const bool up = (lane & (S)) != 0; \
  const float wr = up ? (CC) : 1.0f; \
  const float wi = up ? (SS) : 0.0f; \
  const float sg = up ? -1.0f : 1.0f; \
  const v2f sgv = v2(sg,sg), wrv = v2(wr,wr), wiv = v2(wi,wi); \
  _Pragma("unroll") for (int j = 0; j < 8; ++j) { \
    v2f Zr = Xr[j]*wrv - Xi[j]*wiv; \
    v2f Zi = Xr[j]*wiv + Xi[j]*wrv; \
    v2f Rr = v2(XCHG(Zr.x), XCHG(Zr.y)); \
    v2f Ri = v2(XCHG(Zi.x), XCHG(Zi.y)); \
    Xr[j] = sgv*Zr + Rr; Xi[j] = sgv*Zi + Ri; } }

#define INV_PK_SW(S, SWP, CC, SS) { \
  const bool up = (lane & (S)) != 0; \
  const float wr = up ? (CC) : 1.0f; \
  const float wi = up ? (SS) : 0.0f; \
  const float sg = up ? -1.0f : 1.0f; \
  const v2f sgv = v2(sg,sg), wrv = v2(wr,wr), wiv = v2(wi,wi); \
  _Pragma("unroll") for (int j = 0; j < 8; ++j) { \
    v2f Zr = Xr[j]*wrv - Xi[j]*wiv; \
    v2f Zi = Xr[j]*wiv + Xi[j]*wrv; \
    float l0,h0,l1,h1; \
    SWP(Zr.x,l0,h0); SWP(Zr.y,l1,h1); \
    v2f Lr = v2(l0,l1), Hr = v2(h0,h1); \
    SWP(Zi.x,l0,h0); SWP(Zi.y,l1,h1); \
    v2f Li = v2(l0,l1), Hi = v2(h0,h1); \
    Xr[j] = sgv*Hr + Lr; Xi[j] = sgv*Hi + Li; } }

// Forward DIF x2: natural in -> bit-reversed out, two independent FFTs.
__device__ __forceinline__ void wave_fft512_fwd2(v2f Xr[8], v2f Xi[8], int lane,
                                                 const Tw& t) {
  { // s=256: packed per-k twiddles; second pair uses (Ti0, -Tr0)
    const float c8 = 0.70710678118654752f;
    float wr = t.c[0], wi = -t.s[0];
    float w1r = c8*(wr + wi), w1i = c8*(wi - wr);
    v2f Tr0 = v2(wr, w1r), Ti0 = v2(wi, w1i);
    #pragma unroll
    for (int o = 0; o < 8; o += 4) {
      { v2f Sr = Xr[o]+Xr[o+2], Si = Xi[o]+Xi[o+2];
        v2f Dr = Xr[o]-Xr[o+2], Di = Xi[o]-Xi[o+2];
        Xr[o] = Sr; Xi[o] = Si;
        Xr[o+2] = Dr*Tr0 - Di*Ti0; Xi[o+2] = Dr*Ti0 + Di*Tr0; }
      { v2f Sr = Xr[o+1]+Xr[o+3], Si = Xi[o+1]+Xi[o+3];
        v2f Dr = Xr[o+1]-Xr[o+3], Di = Xi[o+1]-Xi[o+3];
        Xr[o+1] = Sr; Xi[o+1] = Si;
        Xr[o+3] = Dr*Ti0 + Di*Tr0; Xi[o+3] = Di*Ti0 - Dr*Tr0; }
    }
  }
  { // s=128
    v2f Tr = v2(t.c[1], -t.s[1]), Ti = v2(-t.s[1], -t.c[1]);
    #pragma unroll
    for (int j = 0; j < 8; j += 2) {
      v2f Sr = Xr[j]+Xr[j+1], Si = Xi[j]+Xi[j+1];
      v2f Dr = Xr[j]-Xr[j+1], Di = Xi[j]-Xi[j+1];
      Xr[j] = Sr; Xi[j] = Si;
      Xr[j+1] = Dr*Tr - Di*Ti; Xi[j+1] = Dr*Ti + Di*Tr;
    }
  }
  { // s=64: intra-pair, scalar
    float wr = t.c[2], wi = -t.s[2];
    #pragma unroll
    for (int j = 0; j < 8; ++j) {
      float sr = Xr[j].x + Xr[j].y, si = Xi[j].x + Xi[j].y;
      float dr = Xr[j].x - Xr[j].y, di = Xi[j].x - Xi[j].y;
      Xr[j] = v2(sr, dr*wr - di*wi);
      Xi[j] = v2(si, dr*wi + di*wr);
    }
  }
  FWD_PK_SW(32, swp32, t.c[3], t.s[3])
  FWD_PK_SW(16, swp16, t.c[4], t.s[4])
  FWD_PK_XS(8,  xs8,  t.c[5], t.s[5])
  FWD_PK_XS(4,  xs4,  t.c[6], t.s[6])
  FWD_PK_XS(2,  xs2,  t.c[7], t.s[7])
  { // s=1
    const float sg = (lane & 1) ? -1.0f : 1.0f;
    const v2f sgv = v2(sg, sg);
    #pragma unroll
    for (int j = 0; j < 8; ++j) {
      v2f Rr = v2(xs1(Xr[j].x), xs1(Xr[j].y));
      v2f Ri = v2(xs1(Xi[j].x), xs1(Xi[j].y));
      Xr[j] = sgv*Xr[j] + Rr; Xi[j] = sgv*Xi[j] + Ri;
    }
  }
}

// Inverse DIT x2: bit-reversed in -> natural out (unnormalized).
__device__ __forceinline__ void wave_fft512_inv2(v2f Xr[8], v2f Xi[8], int lane,
                                                 const Tw& t) {
  { // s=1
    const float sg = (lane & 1) ? -1.0f : 1.0f;
    const v2f sgv = v2(sg, sg);
    #pragma unroll
    for (int j = 0; j < 8; ++j) {
      v2f Rr = v2(xs1(Xr[j].x), xs1(Xr[j].y));
      v2f Ri = v2(xs1(Xi[j].x), xs1(Xi[j].y));
      Xr[j] = sgv*Xr[j] + Rr; Xi[j] = sgv*Xi[j] + Ri;
    }
  }
  INV_PK_XS(2,  xs2,  t.c[7], t.s[7])
  INV_PK_XS(4,  xs4,  t.c[6], t.s[6])
  INV_PK_XS(8,  xs8,  t.c[5], t.s[5])
  INV_PK_SW(16, swp16, t.c[4], t.s[4])
  INV_PK_SW(32, swp32, t.c[3], t.s[3])
  { // s=64: intra-pair, scalar
    float wr = t.c[2], wi = t.s[2];
    #pragma unroll
    for (int j = 0; j < 8; ++j) {
      float tr = Xr[j].y*wr - Xi[j].y*wi, ti = Xr[j].y*wi + Xi[j].y*wr;
      Xr[j] = v2(Xr[j].x + tr, Xr[j].x - tr);
      Xi[j] = v2(Xi[j].x + ti, Xi[j].x - ti);
    }
  }
  { // s=128
    v2f Tr = v2(t.c[1], -t.s[1]), Ti = v2(t.s[1], t.c[1]);
    #pragma unroll
    for (int j = 0; j < 8; j += 2) {
      v2f tr = Xr[j+1]*Tr - Xi[j+1]*Ti;
      v2f ti = Xr[j+1]*Ti + Xi[j+1]*Tr;
      Xr[j+1] = Xr[j] - tr; Xi[j+1] = Xi[j] - ti;
      Xr[j]   = Xr[j] + tr; Xi[j]   = Xi[j] + ti;
    }
  }
  { // s=256
    const float c8 = 0.70710678118654752f;
    float wr = t.c[0], wi = t.s[0];
    float w1r = c8*(wr - wi), w1i = c8*(wr + wi);
    v2f Tr0 = v2(wr, w1r), Ti0 = v2(wi, w1i);
    #pragma unroll
    for (int o = 0; o < 8; o += 4) {
      { v2f tr = Xr[o+2]*Tr0 - Xi[o+2]*Ti0;
        v2f ti = Xr[o+2]*Ti0 + Xi[o+2]*Tr0;
        Xr[o+2] = Xr[o] - tr; Xi[o+2] = Xi[o] - ti;
        Xr[o]   = Xr[o] + tr; Xi[o]   = Xi[o] + ti; }
      { v2f tr = -(Xr[o+3]*Ti0) - Xi[o+3]*Tr0;
        v2f ti = Xr[o+3]*Tr0 - Xi[o+3]*Ti0;
        Xr[o+3] = Xr[o+1] - tr; Xi[o+3] = Xi[o+1] - ti;
        Xr[o+1] = Xr[o+1] + tr; Xi[o+1] = Xi[o+1] + ti; }
    }
  }
}

// ---------------- kernels ----------------
__global__ void k_scatter(const int* __restrict__ idxx, const int* __restrict__ idxy,
                          const int* __restrict__ cid, int* __restrict__ W) {
  int p = blockIdx.x * 256 + threadIdx.x;
  int u = (idxx[p] + 256) & 511;
  int v = (idxy[p] + 256) & 511;
  atomicMax(&W[u * 512 + v], (p << 6) | cid[p]);
}

__global__ void k_pack(const int* __restrict__ W, int* __restrict__ pk) {
  int idx = blockIdx.x * 256 + threadIdx.x;
  if (idx >= 264 * 512) return;
  int j = idx >> 9, n = idx & 511;
  int out = (127 << 7) | 127;
  if (j < 257) {
    int v = (j == 256) ? 256 : brev9(2 * j);
    int u = brev9(n);
    int c1 = W[u * 512 + v];
    int c2 = W[((512 - u) & 511) * 512 + ((512 - v) & 511)];
    int a = (c1 < 0) ? 127 : (c1 & 63);
    int b = (c2 < 0) ? 127 : (c2 & 63);
    out = (b << 7) | a;
  }
  pk[j * 512 + n] = out;
}

// 4 real rows per wave (two packed FFTs); output TRANSPOSED: Yt[b][j][r].
// Block = 256 threads = 4 waves = 16 rows.
__global__ __launch_bounds__(256) void k_fwd_rows(const float* __restrict__ x,
                                                  float2* __restrict__ Yt) {
  __shared__ float sm[2 * 264 * TP];             // 35.9 KB; z-scratch aliased pre-barrier
  float* tR = sm;
  float* tI = sm + 264 * TP;
  int tid = threadIdx.x, w = tid >> 6, lane = tid & 63;
  int R0 = blockIdx.x * 16;
  int bb = R0 >> 9, r0 = R0 & 511;
  const float* r00 = x + (size_t)(R0 + 4 * w) * 512;   // FFT0: rows +0,+1; FFT1: +2,+3
  Tw t = make_tw(lane);
  v2f Xr[8], Xi[8];
  #pragma unroll
  for (int j = 0; j < 4; ++j) {
    Xr[j]   = v2(r00[(2*j)*64 + lane],        r00[(2*j+1)*64 + lane]);
    Xi[j]   = v2(r00[512 + (2*j)*64 + lane],  r00[512 + (2*j+1)*64 + lane]);
    Xr[4+j] = v2(r00[1024 + (2*j)*64 + lane], r00[1024 + (2*j+1)*64 + lane]);
    Xi[4+j] = v2(r00[1536 + (2*j)*64 + lane], r00[1536 + (2*j+1)*64 + lane]);
  }
  wave_fft512_fwd2(Xr, Xi, lane, t);
  float* zr0 = sm + w * 2048;                    // wave-private scratch (in-order DS)
  float* zi0 = zr0 + 512;
  float* zr1 = zr0 + 1024;
  float* zi1 = zr0 + 1536;
  #pragma unroll
  for (int j = 0; j < 4; ++j) {
    zr0[(2*j)*64 + lane] = Xr[j].x;   zr0[(2*j+1)*64 + lane] = Xr[j].y;
    zi0[(2*j)*64 + lane] = Xi[j].x;   zi0[(2*j+1)*64 + lane] = Xi[j].y;
    zr1[(2*j)*64 + lane] = Xr[4+j].x; zr1[(2*j+1)*64 + lane] = Xr[4+j].y;
    zi1[(2*j)*64 + lane] = Xi[4+j].x; zi1[(2*j+1)*64 + lane] = Xi[4+j].y;
  }
  float ar0[4], ai0[4], br0[4], bi0[4];
  float ar1[4], ai1[4], br1[4], bi1[4];
  #pragma unroll
  for (int k = 0; k < 4; ++k) {                  // split A/B; index math shared by both FFTs
    int j = k * 64 + lane;
    int n2 = 2 * j;
    int kf = brev9(n2);
    int m = brev9((512 - kf) & 511);
    float er = zr0[n2], ei = zi0[n2], mr = zr0[m], mi = zi0[m];
    ar0[k] = 0.5f*(er + mr); ai0[k] = 0.5f*(ei - mi);
    br0[k] = 0.5f*(ei + mi); bi0[k] = 0.5f*(mr - er);
    float er1 = zr1[n2], ei1 = zi1[n2], mr1 = zr1[m], mi1 = zi1[m];
    ar1[k] = 0.5f*(er1 + mr1); ai1[k] = 0.5f*(ei1 - mi1);
    br1[k] = 0.5f*(ei1 + mi1); bi1[k] = 0.5f*(mr1 - er1);
  }
  float a256_0 = zr0[1], b256_0 = zi0[1];
  float a256_1 = zr1[1], b256_1 = zi1[1];
  __syncthreads();                               // all waves done with z-scratch
  #pragma unroll
  for (int k = 0; k < 4; ++k) {                  // tile[j][rr], rows rr = 4w..4w+3
    int j = k * 64 + lane;
    tR[j*TP + 4*w]     = ar0[k]; tI[j*TP + 4*w]     = ai0[k];
    tR[j*TP + 4*w + 1] = br0[k]; tI[j*TP + 4*w + 1] = bi0[k];
    tR[j*TP + 4*w + 2] = ar1[k]; tI[j*TP + 4*w + 2] = ai1[k];
    tR[j*TP + 4*w + 3] = br1[k]; tI[j*TP + 4*w + 3] = bi1[k];
  }
  if (lane == 0) {
    tR[256*TP + 4*w]     = a256_0; tI[256*TP + 4*w]     = 0.0f;
    tR[256*TP + 4*w + 1] = b256_0; tI[256*TP + 4*w + 1] = 0.0f;
    tR[256*TP + 4*w + 2] = a256_1; tI[256*TP + 4*w + 2] = 0.0f;
    tR[256*TP + 4*w + 3] = b256_1; tI[256*TP + 4*w + 3] = 0.0f;
  }
  __syncthreads();
  #pragma unroll
  for (int rep = 0; rep < 17; ++rep) {           // 128B-contiguous chunks per column
    int e = rep * 256 + tid;
    int j = e >> 4, rr = e & 15;
    if (j < 257)
      Yt[((size_t)bb * 264 + j) * 512 + r0 + rr] =
        make_float2(tR[j*TP + rr], tI[j*TP + rr]);
  }
}

// Column FFT + symmetrized mask + inverse column FFT; 2 columns per wave, in-place.
__global__ __launch_bounds__(256) void k_cols(float2* __restrict__ Yt,
                                              const int* __restrict__ pk,
                                              const float* __restrict__ pimp) {
  __shared__ float pilx[128];
  int tid = threadIdx.x;
  int b = blockIdx.x / 33, g = blockIdx.x % 33;
  if (tid < 128) pilx[tid] = (tid < 64) ? pimp[b * 64 + tid] * HALF_INV : HALF_INV;
  int w = tid >> 6, lane = tid & 63;
  int j0 = g * 8 + 2 * w;
  float2* col0 = Yt + ((size_t)b * 264 + j0) * 512;
  float2* col1 = col0 + 512;
  const int* cm0 = pk + j0 * 512;
  const int* cm1 = cm0 + 512;
  int pcm[16];
  v2f Xr[8], Xi[8];
  #pragma unroll
  for (int q = 0; q < 4; ++q) {                  // coalesced loads + pk prefetch (both cols)
    float2 a0 = col0[(2*q)*64 + lane], a1 = col0[(2*q+1)*64 + lane];
    float2 b0 = col1[(2*q)*64 + lane], b1 = col1[(2*q+1)*64 + lane];
    Xr[q]   = v2(a0.x, a1.x); Xi[q]   = v2(a0.y, a1.y);
    Xr[4+q] = v2(b0.x, b1.x); Xi[4+q] = v2(b0.y, b1.y);
    pcm[2*q]     = cm0[(2*q)*64 + lane];
    pcm[2*q+1]   = cm0[(2*q+1)*64 + lane];
    pcm[8+2*q]   = cm1[(2*q)*64 + lane];
    pcm[8+2*q+1] = cm1[(2*q+1)*64 + lane];
  }
  Tw t = make_tw(lane);
  wave_fft512_fwd2(Xr, Xi, lane, t);
  __syncthreads();                               // pilx ready (hidden behind FFT)
  #pragma unroll
  for (int q = 0; q < 8; ++q) {                  // packed symmetrized mask
    int p0 = pcm[2*q], p1 = pcm[2*q+1];
    v2f mv = v2(pilx[p0 & 127] + pilx[(p0 >> 7) & 127],
                pilx[p1 & 127] + pilx[(p1 >> 7) & 127]);
    Xr[q] *= mv; Xi[q] *= mv;
  }
  wave_fft512_inv2(Xr, Xi, lane, t);
  #pragma unroll
  for (int q = 0; q < 4; ++q) {
    col0[(2*q)*64 + lane]   = make_float2(Xr[q].x, Xi[q].x);
    col0[(2*q+1)*64 + lane] = make_float2(Xr[q].y, Xi[q].y);
    col1[(2*q)*64 + lane]   = make_float2(Xr[4+q].x, Xi[4+q].x);
    col1[(2*q+1)*64 + lane] = make_float2(Xr[4+q].y, Xi[4+q].y);
  }
}

// Hermitian mirror + inverse row FFT; 2 row-pairs (4 rows) per wave.
__global__ __launch_bounds__(256) void k_inv_rows(const float2* __restrict__ Yt,
                                                  float* __restrict__ out) {
  __shared__ float tR[264 * TP], tI[264 * TP];
  int tid = threadIdx.x, w = tid >> 6, lane = tid & 63;
  int R0 = blockIdx.x * 16;
  int bb = R0 >> 9, r0 = R0 & 511;
  #pragma unroll
  for (int rep = 0; rep < 17; ++rep) {           // coalesced 128B-chunk tile load
    int e = rep * 256 + tid;
    int j = e >> 4, rr = e & 15;
    if (j < 257) {
      float2 v = Yt[((size_t)bb * 264 + j) * 512 + r0 + rr];
      tR[j*TP + rr] = v.x; tI[j*TP + rr] = v.y;
    }
  }
  Tw t = make_tw(lane);
  __syncthreads();
  v2f Xr[8], Xi[8];
  #pragma unroll
  for (int q = 0; q < 4; ++q) {                  // C = A + i*B; index math shared
    float xr0[2], xi0[2], xr1[2], xi1[2];
    #pragma unroll
    for (int h = 0; h < 2; ++h) {
      int n = (2*q + h) * 64 + lane;
      int v9 = brev9(n);
      int j2 = brev9((512 - v9) & 511) >> 1;
      bool oddx = (n & 1) && (n != 1);
      int j = (n & 1) ? ((n == 1) ? 256 : j2) : (n >> 1);
      float s = oddx ? -1.0f : 1.0f;
      float ar = tR[j*TP + 4*w],     ai = tI[j*TP + 4*w];
      float br = tR[j*TP + 4*w + 1], bi = tI[j*TP + 4*w + 1];
      xr0[h] = ar - s * bi;  xi0[h] = fmaf(s, ai, br);
      float ar1 = tR[j*TP + 4*w + 2], ai1 = tI[j*TP + 4*w + 2];
      float br1 = tR[j*TP + 4*w + 3], bi1 = tI[j*TP + 4*w + 3];
      xr1[h] = ar1 - s * bi1; xi1[h] = fmaf(s, ai1, br1);
    }
    Xr[q]   = v2(xr0[0], xr0[1]); Xi[q]   = v2(xi0[0], xi0[1]);
    Xr[4+q] = v2(xr1[0], xr1[1]); Xi[4+q] = v2(xi1[0], xi1[1]);
  }
  wave_fft512_inv2(Xr, Xi, lane, t);
  float* orA0 = out + (size_t)(R0 + 4 * w) * 512;
  float* orB0 = orA0 + 512;
  float* orA1 = orA0 + 1024;
  float* orB1 = orA0 + 1536;
  #pragma unroll
  for (int q = 0; q < 4; ++q) {
    orA0[(2*q)*64 + lane]   = Xr[q].x;   orA0[(2*q+1)*64 + lane] = Xr[q].y;
    orB0[(2*q)*64 + lane]   = Xi[q].x;   orB0[(2*q+1)*64 + lane] = Xi[q].y;
    orA1[(2*q)*64 + lane]   = Xr[4+q].x; orA1[(2*q+1)*64 + lane] = Xr[4+q].y;
    orB1[(2*q)*64 + lane]   = Xi[4+q].x; orB1[(2*q+1)*64 + lane] = Xi[4+q].y;
  }
}

extern "C" void kernel_launch(void* const* d_in, const int* in_sizes, int n_in,
                              void* d_out, int out_size, void* d_ws, size_t ws_size,
                              hipStream_t stream) {
  const float* x    = (const float*)d_in[0];
  const float* pimp = (const float*)d_in[1];
  const int* idxx   = (const int*)d_in[2];
  const int* idxy   = (const int*)d_in[3];
  const int* cid    = (const int*)d_in[4];

  float2* Yt = (float2*)d_ws;                                    // 69.2 MB
  int* W  = (int*)((char*)d_ws + (size_t)64 * YT_B * sizeof(float2)); // 1 MB
  int* pk = W + 512 * 512;                                       // 0.54 MB

  hipMemsetAsync(W, 0xFF, 512 * 512 * sizeof(int), stream);
  k_scatter  <<<1024, 256, 0, stream>>>(idxx, idxy, cid, W);
  k_pack     <<<(264 * 512 + 255) / 256, 256, 0, stream>>>(W, pk);
  k_fwd_rows <<<2048, 256, 0, stream>>>(x, Yt);
  k_cols     <<<64 * 33, 256, 0, stream>>>(Yt, pk, pimp);
  k_inv_rows <<<2048, 256, 0, stream>>>(Yt, (float*)d_out);
}